// Round 8
// baseline (302.873 us; speedup 1.0000x reference)
//
#include <hip/hip_runtime.h>

typedef unsigned short u16;
typedef unsigned int u32;
typedef __bf16 bf16x8 __attribute__((ext_vector_type(8)));
typedef float f32x4 __attribute__((ext_vector_type(4)));

#define BATCH 4
#define SLEN 2048
#define DMODEL 1024
#define NHEAD 16
#define DHEAD 64
#define MROWS (BATCH * SLEN) /* 8192 */
#define QKS 2048             /* qk buffer row stride (Q|K packed) */

__device__ __forceinline__ u16 f32_to_bf16(float f) {
  u32 u = __float_as_uint(f);
  u32 r = (u + 0x7FFFu + ((u >> 16) & 1u)) >> 16;
  return (u16)r;
}
__device__ __forceinline__ u32 pack_bf16x2(float a, float b) {
  return (u32)f32_to_bf16(a) | ((u32)f32_to_bf16(b) << 16);
}

// pack two f32 -> two bf16 (truncate), 1 v_perm_b32
__device__ __forceinline__ u32 pack_trunc(float lo, float hi) {
#if __has_builtin(__builtin_amdgcn_perm)
  return __builtin_amdgcn_perm(__float_as_uint(hi), __float_as_uint(lo), 0x07060302u);
#else
  return (__float_as_uint(hi) & 0xFFFF0000u) | (__float_as_uint(lo) >> 16);
#endif
}
// pack with round-half-up
__device__ __forceinline__ u32 pack_round(float lo, float hi) {
  u32 ul = __float_as_uint(lo) + 0x8000u;
  u32 uh = __float_as_uint(hi) + 0x8000u;
#if __has_builtin(__builtin_amdgcn_perm)
  return __builtin_amdgcn_perm(uh, ul, 0x07060302u);
#else
  return (uh & 0xFFFF0000u) | (ul >> 16);
#endif
}

#if __has_builtin(__builtin_amdgcn_exp2f)
#define EXP2(x) __builtin_amdgcn_exp2f(x)
#else
#define EXP2(x) exp2f(x)
#endif

// async global->LDS, 16 B per lane; lds dest = wave-uniform base + lane*16
typedef const __attribute__((address_space(1))) void* gas_cv;
typedef __attribute__((address_space(3))) void* las_v;
__device__ __forceinline__ void async16(const u16* g, u16* l) {
  __builtin_amdgcn_global_load_lds((gas_cv)g, (las_v)l, 16, 0, 0);
}

// ---------------- prep kernels ----------------

__global__ void convert_x_kernel(const float* __restrict__ x, u16* __restrict__ xb) {
  size_t i = ((size_t)blockIdx.x * 256 + threadIdx.x) * 8;
  float4 v0 = *(const float4*)(x + i);
  float4 v1 = *(const float4*)(x + i + 4);
  uint4 o;
  o.x = pack_bf16x2(v0.x, v0.y);
  o.y = pack_bf16x2(v0.z, v0.w);
  o.z = pack_bf16x2(v1.x, v1.y);
  o.w = pack_bf16x2(v1.z, v1.w);
  *(uint4*)(xb + i) = o;
}

__global__ void transpose_w_kernel(const float* __restrict__ Wq, const float* __restrict__ Wk,
                                   const float* __restrict__ Wv, const float* __restrict__ Wo,
                                   u16* __restrict__ wqkvt, u16* __restrict__ wot) {
  __shared__ float tile[32][33];
  int z = blockIdx.z;
  const float* src = (z == 0) ? Wq : (z == 1) ? Wk : (z == 2) ? Wv : Wo;
  u16* dst = (z < 3) ? (wqkvt + (size_t)z * DMODEL * DMODEL) : wot;
  int c0 = blockIdx.x * 32, r0 = blockIdx.y * 32;
  int tx = threadIdx.x & 31, ty = threadIdx.x >> 5;
#pragma unroll
  for (int i = 0; i < 4; ++i)
    tile[ty + 8 * i][tx] = src[(size_t)(r0 + ty + 8 * i) * DMODEL + c0 + tx];
  __syncthreads();
#pragma unroll
  for (int i = 0; i < 4; ++i)
    dst[(size_t)(c0 + ty + 8 * i) * DMODEL + r0 + tx] = f32_to_bf16(tile[tx][ty + 8 * i]);
}

__global__ void concat_bias_kernel(const float* __restrict__ bq, const float* __restrict__ bk,
                                   const float* __restrict__ bv, float* __restrict__ bqkv) {
  int i = blockIdx.x * 256 + threadIdx.x;
  float v = (i < 1024) ? bq[i] : (i < 2048) ? bk[i - 1024] : bv[i - 2048];
  bqkv[i] = v;
}

// ---------------- GEMM core (BK=64, XOR-swizzled LDS, global_load_lds) ----------------
// C[m,n] = sum_k A[m,k]*Bt[n,k] + bias[n]. 128x128 tile, BK=64, 4 waves, 16 iters @K=1024.
// LDS layout [row][64] u16; 16B seg s holds global seg s^(row&7) -> conflict-free b128 reads.

#define GEMM_STAGE(Aptr, Bptr, k0)                                                     \
  _Pragma("unroll") for (int c = 0; c < 4; ++c) {                                      \
    const int rr = wv * 32 + c * 8;                                                    \
    async16(Aptr + (size_t)(m0 + rr + lrow8) * K + (k0) + sga * 8, sA + rr * 64);      \
    async16(Bptr + (size_t)(n0 + rr + lrow8) * K + (k0) + sga * 8, sB + rr * 64);      \
  }

#define GEMM_COMPUTE()                                                                 \
  _Pragma("unroll") for (int ks = 0; ks < 2; ++ks) {                                   \
    const int sl = ((ks * 4 + quad) ^ (col & 7)) * 8;                                  \
    bf16x8 af[4], bfr[4];                                                              \
    _Pragma("unroll") for (int i = 0; i < 4; ++i)                                      \
        af[i] = *(const bf16x8*)(sA + (wr * 64 + i * 16 + col) * 64 + sl);             \
    _Pragma("unroll") for (int j = 0; j < 4; ++j)                                      \
        bfr[j] = *(const bf16x8*)(sB + (wc * 64 + j * 16 + col) * 64 + sl);            \
    _Pragma("unroll") for (int i = 0; i < 4; ++i)                                      \
        _Pragma("unroll") for (int j = 0; j < 4; ++j)                                  \
            acc[i][j] = __builtin_amdgcn_mfma_f32_16x16x32_bf16(af[i], bfr[j],         \
                                                                acc[i][j], 0, 0, 0);  \
  }

// generic (out-projection): fp32 output
__global__ __launch_bounds__(256) void gemm_bt_kernel(const u16* __restrict__ A,
                                                      const u16* __restrict__ Bt,
                                                      const float* __restrict__ bias,
                                                      float* __restrict__ Cout,
                                                      int M, int N, int K) {
  __shared__ u16 sA[128 * 64];
  __shared__ u16 sB[128 * 64];
  const int tid = threadIdx.x;
  const int wv = tid >> 6, lane = tid & 63;
  const int wr = wv >> 1, wc = wv & 1;
  const int col = lane & 15, quad = lane >> 4;
  const int lrow8 = lane >> 3, sga = (lane & 7) ^ lrow8;
  const int m0 = blockIdx.x * 128;
  const int n0 = blockIdx.y * 128;

  f32x4 acc[4][4] = {};

  for (int k0 = 0; k0 < K; k0 += 64) {
    GEMM_STAGE(A, Bt, k0)
    __syncthreads();
    GEMM_COMPUTE()
    __syncthreads();
  }

#pragma unroll
  for (int i = 0; i < 4; ++i) {
#pragma unroll
    for (int j = 0; j < 4; ++j) {
      int n = n0 + wc * 64 + j * 16 + col;
      float bia = bias[n];
#pragma unroll
      for (int r = 0; r < 4; ++r) {
        int m = m0 + wr * 64 + i * 16 + quad * 4 + r;
        Cout[(size_t)m * N + n] = acc[i][j][r] + bia;
      }
    }
  }
}

// QKV projection: N=3072. Q,K cols (n<2048) -> qk [8192][2048] bf16 row-major;
// V cols (n>=2048) -> vt [b][h][dh][s] bf16 (transposed, packed 8B stores). Per-block
// uniform branch (n0 is 128-aligned, 2048 boundary aligned).
__global__ __launch_bounds__(256) void gemm_qkv_kernel(const u16* __restrict__ A,
                                                       const u16* __restrict__ Bt,
                                                       const float* __restrict__ bias,
                                                       u16* __restrict__ qk,
                                                       u16* __restrict__ vt) {
  const int K = DMODEL;
  __shared__ u16 sA[128 * 64];
  __shared__ u16 sB[128 * 64];
  const int tid = threadIdx.x;
  const int wv = tid >> 6, lane = tid & 63;
  const int wr = wv >> 1, wc = wv & 1;
  const int col = lane & 15, quad = lane >> 4;
  const int lrow8 = lane >> 3, sga = (lane & 7) ^ lrow8;
  const int m0 = blockIdx.x * 128;
  const int n0 = blockIdx.y * 128;

  f32x4 acc[4][4] = {};

  for (int k0 = 0; k0 < K; k0 += 64) {
    GEMM_STAGE(A, Bt, k0)
    __syncthreads();
    GEMM_COMPUTE()
    __syncthreads();
  }

  if (n0 < 2048) {
    // Q,K: row-major scalar stores into qk
#pragma unroll
    for (int i = 0; i < 4; ++i) {
#pragma unroll
      for (int j = 0; j < 4; ++j) {
        int n = n0 + wc * 64 + j * 16 + col;
        float bia = bias[n];
#pragma unroll
        for (int r = 0; r < 4; ++r) {
          int m = m0 + wr * 64 + i * 16 + quad * 4 + r;
          qk[(size_t)m * QKS + n] = f32_to_bf16(acc[i][j][r] + bia);
        }
      }
    }
  } else {
    // V: transposed packed stores into vt[b][h][dh][s]
#pragma unroll
    for (int i = 0; i < 4; ++i) {
      int m = m0 + wr * 64 + i * 16 + quad * 4; // +r, 4 consecutive, no batch crossing
      int b = m >> 11, s = m & 2047;
#pragma unroll
      for (int j = 0; j < 4; ++j) {
        int n = n0 + wc * 64 + j * 16 + col;
        float bia = bias[n];
        int hd = n - 2048; // h*64+dh
        size_t off = (size_t)((b << 10) | hd) * SLEN + s; // ((b*16+h)*64+dh)*SLEN + s
        uint2 pk;
        pk.x = pack_round(acc[i][j][0] + bia, acc[i][j][1] + bia);
        pk.y = pack_round(acc[i][j][2] + bia, acc[i][j][3] + bia);
        *(uint2*)(vt + off) = pk;
      }
    }
  }
}

// ---------------- flash attention v6: cooperative staging, unpaired, 3 blocks/CU ----------------
// grid (16, BATCH*NHEAD), 256 thr = 4 waves. Wave wv owns strip s2 = (15-bx)*4+wv
// (32 q-rows); longest strips dispatched first (backfill covers drain). Block-uniform
// nt_max = 2*(15-bx)+2 tile iterations; K/V tile staged once per block into
// double-buffered LDS via global_load_lds (XOR(row&7) 16B-seg swizzle), 1 barrier/tile.
__global__ __launch_bounds__(256, 3) void attn_kernel(const u16* __restrict__ qk,
                                                      const u16* __restrict__ vt,
                                                      u16* __restrict__ out) {
  const int bh = blockIdx.y;
  const int b = bh >> 4, h = bh & 15;
  const int tid = threadIdx.x;
  const int wv = tid >> 6, lane = tid & 63;
  const int col = lane & 15, quad = lane >> 4;
  const int bxr = 15 - (int)blockIdx.x; // longest first
  const int s2 = bxr * 4 + wv;          // 0..63
  const int qbase = s2 * 32;
  const int nt_own = s2 / 2 + 1;
  const int nt_max = 2 * bxr + 2; // block-uniform

  __shared__ u16 sK[2][64 * 64];
  __shared__ u16 sV[2][64 * 64];
  __shared__ u16 sP[4][32 * 72];
  u16* mysP = sP[wv];

  const u16* kbase = qk + ((size_t)(b * SLEN)) * QKS + 1024 + h * DHEAD;
  const u16* vbase = vt + ((size_t)bh * DHEAD) * SLEN;
  const float scl2 = 0.125f * 1.44269504088896f; // 1/sqrt(dh) * log2(e)

  // staging: wave wv stages rows [wv*16, wv*16+16) of K and V^T tiles (2 calls each).
  const int lrow = lane >> 3;
  const int sga = (lane & 7) ^ lrow; // swizzled global 16B-seg
  const int r0a = wv * 16, r0b = wv * 16 + 8;

  const u16* qrow = qk + ((size_t)(b * SLEN + qbase + col)) * QKS + h * DHEAD;
  bf16x8 aQ[2][2]; // Q as MFMA B operand: [i=q-16block][ks]
#pragma unroll
  for (int i = 0; i < 2; ++i)
#pragma unroll
    for (int ks = 0; ks < 2; ++ks)
      aQ[i][ks] = *(const bf16x8*)(qrow + (size_t)i * 16 * QKS + ks * 32 + quad * 8);

  f32x4 accO[2][4] = {}; // [i][j]: col=q, rows=dh
  float m2[2] = {-1e30f, -1e30f}, l_i[2] = {0.0f, 0.0f};

  // prologue: stage tile 0 into buffer 0
  async16(kbase + (size_t)(r0a + lrow) * QKS + sga * 8, sK[0] + r0a * 64);
  async16(kbase + (size_t)(r0b + lrow) * QKS + sga * 8, sK[0] + r0b * 64);
  async16(vbase + (size_t)(r0a + lrow) * SLEN + sga * 8, sV[0] + r0a * 64);
  async16(vbase + (size_t)(r0b + lrow) * SLEN + sga * 8, sV[0] + r0b * 64);
  __syncthreads();

  for (int t = 0; t < nt_max; ++t) {
    const int kv0 = t * 64;
    const int cur = t & 1, nxt = cur ^ 1;

    // prefetch next tile into the other buffer (drained by this iteration's end barrier)
    if (t + 1 < nt_max) {
      const int kvn = kv0 + 64;
      async16(kbase + (size_t)(kvn + r0a + lrow) * QKS + sga * 8, sK[nxt] + r0a * 64);
      async16(kbase + (size_t)(kvn + r0b + lrow) * QKS + sga * 8, sK[nxt] + r0b * 64);
      async16(vbase + (size_t)(r0a + lrow) * SLEN + kvn + sga * 8, sV[nxt] + r0a * 64);
      async16(vbase + (size_t)(r0b + lrow) * SLEN + kvn + sga * 8, sV[nxt] + r0b * 64);
    }

    if (t < nt_own) {
      const u16* sKc = sK[cur];
      const u16* sVc = sV[cur];
      bf16x8 bK[2][4], bV[2][4];
#pragma unroll
      for (int ks = 0; ks < 2; ++ks) {
        const int sl = (((ks * 4 + quad) ^ (col & 7)) * 8);
#pragma unroll
        for (int cb = 0; cb < 4; ++cb)
          bK[ks][cb] = *(const bf16x8*)(sKc + (cb * 16 + col) * 64 + sl);
#pragma unroll
        for (int j = 0; j < 4; ++j)
          bV[ks][j] = *(const bf16x8*)(sVc + (j * 16 + col) * 64 + sl);
      }

      // S^T = K Q^T : accST[i][cb] col=q=i*16+col, row=kv=cb*16+quad*4+r (raw)
      f32x4 accST[2][4] = {};
#pragma unroll
      for (int ks = 0; ks < 2; ++ks)
#pragma unroll
        for (int cb = 0; cb < 4; ++cb)
#pragma unroll
          for (int i = 0; i < 2; ++i)
            accST[i][cb] = __builtin_amdgcn_mfma_f32_16x16x32_bf16(bK[ks][cb], aQ[i][ks],
                                                                  accST[i][cb], 0, 0, 0);

      // causal mask on diagonal tile (raw domain)
      if (t == nt_own - 1) {
#pragma unroll
        for (int i = 0; i < 2; ++i) {
          int q = qbase + i * 16 + col;
#pragma unroll
          for (int cb = 0; cb < 4; ++cb) {
            int kvb = kv0 + cb * 16 + quad * 4;
#pragma unroll
            for (int r = 0; r < 4; ++r)
              if (kvb + r > q) accST[i][cb][r] = -1e30f;
          }
        }
      }

      // online softmax (exp2 domain): in-reg fmax + 2 shfl per i-block
      float rmax[2], mnew[2], alpha[2], rsum[2];
#pragma unroll
      for (int i = 0; i < 2; ++i) {
        float m = accST[i][0][0];
#pragma unroll
        for (int cb = 0; cb < 4; ++cb)
#pragma unroll
          for (int r = 0; r < 4; ++r) m = fmaxf(m, accST[i][cb][r]);
        rmax[i] = m;
      }
#pragma unroll
      for (int i = 0; i < 2; ++i) {
        rmax[i] = fmaxf(rmax[i], __shfl_xor(rmax[i], 16));
        rmax[i] = fmaxf(rmax[i], __shfl_xor(rmax[i], 32));
        mnew[i] = fmaxf(m2[i], rmax[i] * scl2);
        alpha[i] = EXP2(m2[i] - mnew[i]);
        m2[i] = mnew[i];
      }
#pragma unroll
      for (int i = 0; i < 2; ++i) {
        float sacc = 0.0f;
#pragma unroll
        for (int cb = 0; cb < 4; ++cb)
#pragma unroll
          for (int r = 0; r < 4; ++r) {
            float p = EXP2(__builtin_fmaf(accST[i][cb][r], scl2, -mnew[i]));
            accST[i][cb][r] = p;
            sacc += p;
          }
        rsum[i] = sacc;
      }
#pragma unroll
      for (int i = 0; i < 2; ++i) {
        rsum[i] += __shfl_xor(rsum[i], 16);
        rsum[i] += __shfl_xor(rsum[i], 32);
        l_i[i] = l_i[i] * alpha[i] + rsum[i];
      }
#pragma unroll
      for (int i = 0; i < 2; ++i)
#pragma unroll
        for (int j = 0; j < 4; ++j)
#pragma unroll
          for (int r = 0; r < 4; ++r) accO[i][j][r] *= alpha[i];

      // P^T -> per-wave LDS packed (b64 per (i,cb)), read back as B-frags (intra-wave)
#pragma unroll
      for (int i = 0; i < 2; ++i)
#pragma unroll
        for (int cb = 0; cb < 4; ++cb) {
          uint2 pk;
          pk.x = pack_trunc(accST[i][cb][0], accST[i][cb][1]);
          pk.y = pack_trunc(accST[i][cb][2], accST[i][cb][3]);
          *(uint2*)(mysP + (i * 16 + col) * 72 + cb * 16 + quad * 4) = pk;
        }
      bf16x8 aP[2][2];
#pragma unroll
      for (int i = 0; i < 2; ++i)
#pragma unroll
        for (int ks = 0; ks < 2; ++ks)
          aP[i][ks] = *(const bf16x8*)(mysP + (i * 16 + col) * 72 + ks * 32 + quad * 8);

      // O^T += V^T P^T
#pragma unroll
      for (int ks = 0; ks < 2; ++ks)
#pragma unroll
        for (int j = 0; j < 4; ++j)
#pragma unroll
          for (int i = 0; i < 2; ++i)
            accO[i][j] = __builtin_amdgcn_mfma_f32_16x16x32_bf16(bV[ks][j], aP[i][ks],
                                                                accO[i][j], 0, 0, 0);
    }

    __syncthreads(); // all waves done reading cur; drains prefetch into nxt
  }

  // epilogue: O^T col=q row=dh -> out[q][dh], packed dwordx2 stores
#pragma unroll
  for (int i = 0; i < 2; ++i) {
    float rl = 1.0f / l_i[i];
    size_t rowoff = ((size_t)(b * SLEN + qbase + i * 16 + col)) * DMODEL + h * DHEAD;
#pragma unroll
    for (int j = 0; j < 4; ++j) {
      uint2 pk;
      pk.x = pack_round(accO[i][j][0] * rl, accO[i][j][1] * rl);
      pk.y = pack_round(accO[i][j][2] * rl, accO[i][j][3] * rl);
      *(uint2*)(out + rowoff + j * 16 + quad * 4) = pk;
    }
  }
}

// ---------------- launch ----------------

extern "C" void kernel_launch(void* const* d_in, const int* in_sizes, int n_in,
                              void* d_out, int out_size, void* d_ws, size_t ws_size,
                              hipStream_t stream) {
  const float* x = (const float*)d_in[0];
  const float* Wq = (const float*)d_in[1];
  const float* bq = (const float*)d_in[2];
  const float* Wk = (const float*)d_in[3];
  const float* bk = (const float*)d_in[4];
  const float* Wv = (const float*)d_in[5];
  const float* bv = (const float*)d_in[6];
  const float* Wo = (const float*)d_in[7];
  const float* bo = (const float*)d_in[8];

  char* ws = (char*)d_ws;
  u16* xb = (u16*)ws;                              // 16 MB
  u16* wqkvt = (u16*)(ws + ((size_t)16 << 20));    // 6 MB
  u16* wot = (u16*)(ws + ((size_t)22 << 20));      // 2 MB
  u16* qk = (u16*)(ws + ((size_t)24 << 20));       // 32 MB [8192][2048] bf16
  u16* vtp = (u16*)(ws + ((size_t)56 << 20));      // 16 MB [64][64][2048] bf16
  u16* attnO = (u16*)(ws + ((size_t)72 << 20));    // 16 MB
  float* bqkv = (float*)(ws + ((size_t)88 << 20)); // 12 KB

  convert_x_kernel<<<4096, 256, 0, stream>>>(x, xb);
  transpose_w_kernel<<<dim3(32, 32, 4), 256, 0, stream>>>(Wq, Wk, Wv, Wo, wqkvt, wot);
  concat_bias_kernel<<<12, 256, 0, stream>>>(bq, bk, bv, bqkv);
  // QKV projection with fused V-transpose: [8192,1024] x [1024,3072]
  gemm_qkv_kernel<<<dim3(64, 24), 256, 0, stream>>>(xb, wqkvt, bqkv, qk, vtp);
  attn_kernel<<<dim3(16, BATCH * NHEAD), 256, 0, stream>>>(qk, vtp, attnO);
  // out = O @ Wo + bo : [8192,1024] x [1024,1024], fp32 out
  gemm_bt_kernel<<<dim3(64, 8), 256, 0, stream>>>(attnO, wot, bo, (float*)d_out,
                                                  MROWS, DMODEL, DMODEL);
}